// Round 2
// baseline (185.319 us; speedup 1.0000x reference)
//
#include <hip/hip_runtime.h>
#include <hip/hip_fp16.h>
#include <stdint.h>

// Problem constants (fixed by the reference):
#define MQ 8192   // N*C queries
#define NK 1024   // K codewords
#define DD 1024   // H*W
#define SCALE_LO 2048.0f         // 2^11: lift f16 lo-parts out of subnormal range
#define INV_LO   (1.0f / 2048.0f)

typedef _Float16 half8_t __attribute__((ext_vector_type(8)));
typedef _Float16 half4_t __attribute__((ext_vector_type(4)));
typedef float    floatx4 __attribute__((ext_vector_type(4)));

// ---------------- split x into f16 hi/lo (lo pre-scaled by 2^11) ----------------
__global__ void k_split_x(const float* __restrict__ x,
                          _Float16* __restrict__ ah, _Float16* __restrict__ al) {
  int i = blockIdx.x * blockDim.x + threadIdx.x;  // one float4 per thread
  float4 v = ((const float4*)x)[i];
  float vv[4] = {v.x, v.y, v.z, v.w};
  half4_t h, l;
#pragma unroll
  for (int j = 0; j < 4; ++j) {
    _Float16 hh = (_Float16)vv[j];
    h[j] = hh;
    l[j] = (_Float16)((vv[j] - (float)hh) * SCALE_LO);  // (v-h) exact in fp32
  }
  ((half4_t*)ah)[i] = h;
  ((half4_t*)al)[i] = l;
}

// ------------- split codebook + exact-ish row norms (fp64 accum) -------------
// stores csqr[k] = sum(c^2) - 1024 as fp32 (subtract mean magnitude -> small ulp)
__global__ void k_split_cb(const float* __restrict__ cb,
                           _Float16* __restrict__ bh, _Float16* __restrict__ bl,
                           float* __restrict__ csqr) {
  int k = blockIdx.x;
  int t = threadIdx.x;
  float4 v = ((const float4*)(cb + (size_t)k * DD))[t];
  float vv[4] = {v.x, v.y, v.z, v.w};
  half4_t h, l;
  double s = 0.0;
#pragma unroll
  for (int j = 0; j < 4; ++j) {
    _Float16 hh = (_Float16)vv[j];
    h[j] = hh;
    l[j] = (_Float16)((vv[j] - (float)hh) * SCALE_LO);
    s += (double)vv[j] * (double)vv[j];
  }
  ((half4_t*)(bh + (size_t)k * DD))[t] = h;
  ((half4_t*)(bl + (size_t)k * DD))[t] = l;
  // wave64 butterfly, then 4-wave LDS combine
  for (int m = 32; m >= 1; m >>= 1) s += __shfl_xor(s, m, 64);
  __shared__ double red[4];
  if ((t & 63) == 0) red[t >> 6] = s;
  __syncthreads();
  if (t == 0) csqr[k] = (float)(red[0] + red[1] + red[2] + red[3] - 1024.0);
}

__global__ void k_init_keys(unsigned long long* keys) {
  keys[blockIdx.x * blockDim.x + threadIdx.x] = ~0ULL;
}

__device__ __forceinline__ unsigned sortable_u32(float f) {
  unsigned u = __float_as_uint(f);
  return (u & 0x80000000u) ? ~u : (u | 0x80000000u);
}

// ---------------- fused f16x3 GEMM (M=8192,N=1024,Kvirt=3072) + argmin ----------------
// seg0: Ah*Bl' , seg1: Al'*Bh  (both scaled 2^11)  -> acc *= 2^-11 -> seg2: Ah*Bh
__global__ __launch_bounds__(256) void k_gemm_argmin(
    const _Float16* __restrict__ Ah, const _Float16* __restrict__ Al,
    const _Float16* __restrict__ Bh, const _Float16* __restrict__ Bl,
    const float* __restrict__ csqr, unsigned long long* __restrict__ keys) {
  __shared__ _Float16 sA[128 * 32];  // row-major [row][32], unpadded (m97 layout)
  __shared__ _Float16 sB[128 * 32];

  const int tid = threadIdx.x;
  const int bn = blockIdx.x;          // 0..7   (N tiles)  -- fast dim: A-tile reuse in L2/L3
  const int bm = blockIdx.y;          // 0..63  (M tiles)
  const int m0 = bm * 128, n0 = bn * 128;
  const int wave = tid >> 6, lane = tid & 63;
  const int wm = wave & 1, wn = wave >> 1;
  const int quad = lane >> 4, l15 = lane & 15;

  floatx4 acc[4][4];
#pragma unroll
  for (int i = 0; i < 4; ++i)
#pragma unroll
    for (int j = 0; j < 4; ++j) acc[i][j] = (floatx4){0.f, 0.f, 0.f, 0.f};

  // staging: chunk q = tid (rows 0..63) and tid+256 (rows 64..127); 16B per chunk
  const int r0 = tid >> 2;
  const int c0 = (tid & 3) * 8;

  for (int kb = 0; kb < 96; ++kb) {
    const int seg = kb >> 5;
    const _Float16* Ap = (seg == 1) ? Al : Ah;
    const _Float16* Bp = (seg == 0) ? Bl : Bh;
    const int kk = (kb & 31) * 32;

    half8_t a0 = *(const half8_t*)(Ap + (size_t)(m0 + r0) * DD + kk + c0);
    half8_t a1 = *(const half8_t*)(Ap + (size_t)(m0 + r0 + 64) * DD + kk + c0);
    half8_t b0 = *(const half8_t*)(Bp + (size_t)(n0 + r0) * DD + kk + c0);
    half8_t b1 = *(const half8_t*)(Bp + (size_t)(n0 + r0 + 64) * DD + kk + c0);

    if (kb == 64) {  // rescale the 2^11-scaled lo-segments before hi*hi accumulates
#pragma unroll
      for (int i = 0; i < 4; ++i)
#pragma unroll
        for (int j = 0; j < 4; ++j) acc[i][j] *= INV_LO;
    }

    __syncthreads();  // prior iteration's fragment reads done
    *(half8_t*)(sA + (size_t)tid * 8) = a0;
    *(half8_t*)(sA + (size_t)(tid + 256) * 8) = a1;
    *(half8_t*)(sB + (size_t)tid * 8) = b0;
    *(half8_t*)(sB + (size_t)(tid + 256) * 8) = b1;
    __syncthreads();

    half8_t af[4], bf[4];
#pragma unroll
    for (int i = 0; i < 4; ++i)
      af[i] = *(const half8_t*)(sA + (wm * 64 + i * 16 + l15) * 32 + quad * 8);
#pragma unroll
    for (int j = 0; j < 4; ++j)
      bf[j] = *(const half8_t*)(sB + (wn * 64 + j * 16 + l15) * 32 + quad * 8);
#pragma unroll
    for (int i = 0; i < 4; ++i)
#pragma unroll
      for (int j = 0; j < 4; ++j)
        acc[i][j] = __builtin_amdgcn_mfma_f32_16x16x32_f16(af[i], bf[j], acc[i][j], 0, 0, 0);
  }

  // epilogue: score = csqr[n] - 2*dot ; pack (sortable_score, n) ; per-row argmin
  float csv[4];
#pragma unroll
  for (int j = 0; j < 4; ++j) csv[j] = csqr[n0 + wn * 64 + j * 16 + l15];

#pragma unroll
  for (int i = 0; i < 4; ++i) {
#pragma unroll
    for (int r = 0; r < 4; ++r) {
      const int row = m0 + wm * 64 + i * 16 + quad * 4 + r;  // C/D: col=lane&15, row=quad*4+reg
      unsigned long long best = ~0ULL;
#pragma unroll
      for (int j = 0; j < 4; ++j) {
        float s = csv[j] - 2.0f * acc[i][j][r];
        unsigned long long key = ((unsigned long long)sortable_u32(s) << 32) |
                                 (unsigned)(n0 + wn * 64 + j * 16 + l15);
        best = key < best ? key : best;
      }
#pragma unroll
      for (int m = 1; m <= 8; m <<= 1) {  // reduce over the 16 cols held by this quad-group
        unsigned long long o = __shfl_xor(best, m, 64);
        best = o < best ? o : best;
      }
      if (l15 == 0) atomicMin(&keys[row], best);
    }
  }
}

// ---------------- gather winning codeword, write both tuple outputs ----------------
// Overwrites ALL of d_out (including the regions used as f16 scratch earlier).
__global__ void k_gather(const unsigned long long* __restrict__ keys,
                         const float* __restrict__ cb, float* __restrict__ out) {
  int m = blockIdx.x;
  int idx = (int)(keys[m] & 0xFFFFFFFFULL);
  float4 v = ((const float4*)(cb + (size_t)idx * DD))[threadIdx.x];
  ((float4*)(out + (size_t)m * DD))[threadIdx.x] = v;
  ((float4*)(out + (size_t)(m + MQ) * DD))[threadIdx.x] = v;
}

extern "C" void kernel_launch(void* const* d_in, const int* in_sizes, int n_in,
                              void* d_out, int out_size, void* d_ws, size_t ws_size,
                              hipStream_t stream) {
  const float* x = (const float*)d_in[0];
  const float* cb = (const float*)d_in[1];
  float* out = (float*)d_out;

  // Big f16 scratch lives inside d_out (64 MB, fully overwritten by k_gather at
  // the end). d_ws only holds 68 KB (csqr + keys) — round 1's d_ws overflow
  // (36 MB assumed, OOB writes corrupted the harness's pristine input copy) is
  // what made replays diverge.
  char* ob = (char*)d_out;
  _Float16* Ah = (_Float16*)(ob);                                   // 16 MB
  _Float16* Al = (_Float16*)(ob + (size_t)16 * 1024 * 1024);        // 16 MB
  _Float16* Bh = (_Float16*)(ob + (size_t)32 * 1024 * 1024);        // 2 MB
  _Float16* Bl = (_Float16*)(ob + (size_t)34 * 1024 * 1024);        // 2 MB

  char* ws = (char*)d_ws;
  float* csqr = (float*)(ws);                                       // 4 KB
  unsigned long long* keys = (unsigned long long*)(ws + 4096);      // 64 KB

  k_split_x<<<(MQ * DD) / 1024, 256, 0, stream>>>(x, Ah, Al);
  k_split_cb<<<NK, 256, 0, stream>>>(cb, Bh, Bl, csqr);
  k_init_keys<<<MQ / 256, 256, 0, stream>>>(keys);
  k_gemm_argmin<<<dim3(8, 64), 256, 0, stream>>>(Ah, Al, Bh, Bl, csqr, keys);
  k_gather<<<MQ, 256, 0, stream>>>(keys, cb, out);
}

// Round 3
// 182.025 us; speedup vs baseline: 1.0181x; 1.0181x over previous
//
#include <hip/hip_runtime.h>
#include <hip/hip_fp16.h>
#include <stdint.h>

// Problem constants (fixed by the reference):
#define MQ 8192   // N*C queries
#define NK 1024   // K codewords
#define DD 1024   // H*W
#define SCALE_LO 2048.0f         // 2^11: lift f16 lo-parts out of subnormal range
#define INV_LO   (1.0f / 2048.0f)

typedef _Float16 half8_t __attribute__((ext_vector_type(8)));
typedef _Float16 half4_t __attribute__((ext_vector_type(4)));
typedef float    floatx4 __attribute__((ext_vector_type(4)));

// async global->LDS, 16B per lane; LDS dest is wave-uniform base + lane*16
#define GLOAD_LDS16(gp, lp)                                                   \
  __builtin_amdgcn_global_load_lds(                                           \
      (const __attribute__((address_space(1))) void*)(gp),                    \
      (__attribute__((address_space(3))) void*)(lp), 16, 0, 0)

// ---------- fused prep: split x, split codebook (+norms), init keys ----------
// blocks [0,8192): split x (one float4 per thread)
// blocks [8192,9216): split codebook row k + fp64 row norm; k<32 also init keys
__global__ void k_prep(const float* __restrict__ x, const float* __restrict__ cb,
                       _Float16* __restrict__ ah, _Float16* __restrict__ al,
                       _Float16* __restrict__ bh, _Float16* __restrict__ bl,
                       float* __restrict__ csqr,
                       unsigned long long* __restrict__ keys) {
  const int bid = blockIdx.x;
  const int t = threadIdx.x;
  if (bid < 8192) {
    int i = bid * 256 + t;
    float4 v = ((const float4*)x)[i];
    float vv[4] = {v.x, v.y, v.z, v.w};
    half4_t h, l;
#pragma unroll
    for (int j = 0; j < 4; ++j) {
      _Float16 hh = (_Float16)vv[j];
      h[j] = hh;
      l[j] = (_Float16)((vv[j] - (float)hh) * SCALE_LO);  // (v-h) exact in fp32
    }
    ((half4_t*)ah)[i] = h;
    ((half4_t*)al)[i] = l;
  } else {
    int k = bid - 8192;
    if (k < 32) keys[k * 256 + t] = ~0ULL;
    float4 v = ((const float4*)(cb + (size_t)k * DD))[t];
    float vv[4] = {v.x, v.y, v.z, v.w};
    half4_t h, l;
    double s = 0.0;
#pragma unroll
    for (int j = 0; j < 4; ++j) {
      _Float16 hh = (_Float16)vv[j];
      h[j] = hh;
      l[j] = (_Float16)((vv[j] - (float)hh) * SCALE_LO);
      s += (double)vv[j] * (double)vv[j];
    }
    ((half4_t*)(bh + (size_t)k * DD))[t] = h;
    ((half4_t*)(bl + (size_t)k * DD))[t] = l;
    for (int m = 32; m >= 1; m >>= 1) s += __shfl_xor(s, m, 64);
    __shared__ double red[4];
    if ((t & 63) == 0) red[t >> 6] = s;
    __syncthreads();
    if (t == 0) csqr[k] = (float)(red[0] + red[1] + red[2] + red[3] - 1024.0);
  }
}

__device__ __forceinline__ unsigned sortable_u32(float f) {
  unsigned u = __float_as_uint(f);
  return (u & 0x80000000u) ? ~u : (u | 0x80000000u);
}

// ---------------- fused f16x3 GEMM (M=8192,N=1024,Kvirt=3072) + argmin ----------------
// seg0: Ah*Bl' , seg1: Al'*Bh  (both scaled 2^11)  -> acc *= 2^-11 -> seg2: Ah*Bh
__global__ __launch_bounds__(256) void k_gemm_argmin(
    const _Float16* __restrict__ Ah, const _Float16* __restrict__ Al,
    const _Float16* __restrict__ Bh, const _Float16* __restrict__ Bl,
    const float* __restrict__ csqr, unsigned long long* __restrict__ keys) {
  __shared__ _Float16 sA[128 * 32];  // row-major [row][32], unpadded (m97 layout;
  __shared__ _Float16 sB[128 * 32];  // global_load_lds forbids padding)

  const int tid = threadIdx.x;
  const int bn = blockIdx.x;          // 0..7   (N tiles)
  const int bm = blockIdx.y;          // 0..63  (M tiles)
  const int m0 = bm * 128, n0 = bn * 128;
  const int wave = tid >> 6, lane = tid & 63;
  const int wm = wave & 1, wn = wave >> 1;
  const int quad = lane >> 4, l15 = lane & 15;

  floatx4 acc[4][4];
#pragma unroll
  for (int i = 0; i < 4; ++i)
#pragma unroll
    for (int j = 0; j < 4; ++j) acc[i][j] = (floatx4){0.f, 0.f, 0.f, 0.f};

  // staging: chunk = tid covers rows 0..63 (4 lanes x 16B per row), chunk tid+256
  // covers rows 64..127. LDS linear = chunk*16B -> row-major [row][32] halfs.
  const int r0 = tid >> 2;
  const int c0 = (tid & 3) * 8;
  _Float16* sAw = sA + wave * 512;           // wave-uniform LDS bases (halfs)
  _Float16* sAw2 = sA + 2048 + wave * 512;
  _Float16* sBw = sB + wave * 512;
  _Float16* sBw2 = sB + 2048 + wave * 512;

  for (int kb = 0; kb < 96; ++kb) {
    const int seg = kb >> 5;
    const _Float16* Ap = (seg == 1) ? Al : Ah;
    const _Float16* Bp = (seg == 0) ? Bl : Bh;
    const int kk = (kb & 31) * 32;

    if (kb == 64) {  // rescale the 2^11-scaled lo-segments before hi*hi accumulates
#pragma unroll
      for (int i = 0; i < 4; ++i)
#pragma unroll
        for (int j = 0; j < 4; ++j) acc[i][j] *= INV_LO;
    }

    __syncthreads();  // prior iteration's fragment reads done
    GLOAD_LDS16(Ap + (size_t)(m0 + r0) * DD + kk + c0, sAw);
    GLOAD_LDS16(Ap + (size_t)(m0 + 64 + r0) * DD + kk + c0, sAw2);
    GLOAD_LDS16(Bp + (size_t)(n0 + r0) * DD + kk + c0, sBw);
    GLOAD_LDS16(Bp + (size_t)(n0 + 64 + r0) * DD + kk + c0, sBw2);
    __syncthreads();  // drains vmcnt -> LDS tile complete

    half8_t af[4], bf[4];
#pragma unroll
    for (int i = 0; i < 4; ++i)
      af[i] = *(const half8_t*)(sA + (wm * 64 + i * 16 + l15) * 32 + quad * 8);
#pragma unroll
    for (int j = 0; j < 4; ++j)
      bf[j] = *(const half8_t*)(sB + (wn * 64 + j * 16 + l15) * 32 + quad * 8);
#pragma unroll
    for (int i = 0; i < 4; ++i)
#pragma unroll
      for (int j = 0; j < 4; ++j)
        acc[i][j] = __builtin_amdgcn_mfma_f32_16x16x32_f16(af[i], bf[j], acc[i][j], 0, 0, 0);
  }

  // epilogue: score = csqr[n] - 2*dot ; pack (sortable_score, n) ; per-row argmin
  float csv[4];
#pragma unroll
  for (int j = 0; j < 4; ++j) csv[j] = csqr[n0 + wn * 64 + j * 16 + l15];

#pragma unroll
  for (int i = 0; i < 4; ++i) {
#pragma unroll
    for (int r = 0; r < 4; ++r) {
      const int row = m0 + wm * 64 + i * 16 + quad * 4 + r;  // C/D: col=lane&15, row=quad*4+reg
      unsigned long long best = ~0ULL;
#pragma unroll
      for (int j = 0; j < 4; ++j) {
        float s = csv[j] - 2.0f * acc[i][j][r];
        unsigned long long key = ((unsigned long long)sortable_u32(s) << 32) |
                                 (unsigned)(n0 + wn * 64 + j * 16 + l15);
        best = key < best ? key : best;
      }
#pragma unroll
      for (int m = 1; m <= 8; m <<= 1) {  // reduce over the 16 cols held by this quad-group
        unsigned long long o = __shfl_xor(best, m, 64);
        best = o < best ? o : best;
      }
      if (l15 == 0) atomicMin(&keys[row], best);
    }
  }
}

// ---------------- gather winning codeword, write both tuple outputs ----------------
// Overwrites ALL of d_out (including the regions used as f16 scratch earlier).
__global__ void k_gather(const unsigned long long* __restrict__ keys,
                         const float* __restrict__ cb, float* __restrict__ out) {
  int m = blockIdx.x;
  int idx = (int)(keys[m] & 0xFFFFFFFFULL);
  float4 v = ((const float4*)(cb + (size_t)idx * DD))[threadIdx.x];
  ((float4*)(out + (size_t)m * DD))[threadIdx.x] = v;
  ((float4*)(out + (size_t)(m + MQ) * DD))[threadIdx.x] = v;
}

extern "C" void kernel_launch(void* const* d_in, const int* in_sizes, int n_in,
                              void* d_out, int out_size, void* d_ws, size_t ws_size,
                              hipStream_t stream) {
  const float* x = (const float*)d_in[0];
  const float* cb = (const float*)d_in[1];
  float* out = (float*)d_out;

  // Big f16 scratch lives inside d_out (64 MB, fully overwritten by k_gather at
  // the end). d_ws only holds 68 KB (csqr + keys) — R1's d_ws overflow corrupted
  // the harness's pristine inputs; never assume ws_size.
  char* ob = (char*)d_out;
  _Float16* Ah = (_Float16*)(ob);                                   // 16 MB
  _Float16* Al = (_Float16*)(ob + (size_t)16 * 1024 * 1024);        // 16 MB
  _Float16* Bh = (_Float16*)(ob + (size_t)32 * 1024 * 1024);        // 2 MB
  _Float16* Bl = (_Float16*)(ob + (size_t)34 * 1024 * 1024);        // 2 MB

  char* ws = (char*)d_ws;
  float* csqr = (float*)(ws);                                       // 4 KB
  unsigned long long* keys = (unsigned long long*)(ws + 4096);      // 64 KB

  k_prep<<<8192 + 1024, 256, 0, stream>>>(x, cb, Ah, Al, Bh, Bl, csqr, keys);
  k_gemm_argmin<<<dim3(8, 64), 256, 0, stream>>>(Ah, Al, Bh, Bl, csqr, keys);
  k_gather<<<MQ, 256, 0, stream>>>(keys, cb, out);
}